// Round 13
// baseline (2894.926 us; speedup 1.0000x reference)
//
#include <hip/hip_runtime.h>
#include <hip/hip_bf16.h>

#define V 49152
#define NNZ 9
#define EPSV 1e-5f
#define SLOPE 0.1f
#define GRID_CH 768   // chain grid: 768 blocks = 3/CU worst case; 4/CU capacity guaranteed by launch_bounds(256,4)

typedef __attribute__((ext_vector_type(8))) short bf16x8;   // 8 bf16 (4 VGPRs)
typedef __attribute__((ext_vector_type(4))) float f32x4;    // MFMA C/D

__device__ __forceinline__ float lo2f(unsigned u) { return __uint_as_float(u << 16); }
__device__ __forceinline__ float hi2f(unsigned u) { return __uint_as_float(u & 0xffff0000u); }
__device__ __forceinline__ unsigned short f2us(float f) {
    __hip_bfloat16 h = __float2bfloat16(f);
    return *(unsigned short*)&h;
}
__device__ __forceinline__ float us2f(unsigned short u) { return __uint_as_float(((unsigned)u) << 16); }
__device__ __forceinline__ unsigned pk2(float a, float b) {
    return ((unsigned)f2us(a)) | (((unsigned)f2us(b)) << 16);
}
__device__ __forceinline__ void up8(uint4 u, float* e) {
    e[0]=lo2f(u.x); e[1]=hi2f(u.x); e[2]=lo2f(u.y); e[3]=hi2f(u.y);
    e[4]=lo2f(u.z); e[5]=hi2f(u.z); e[6]=lo2f(u.w); e[7]=hi2f(u.w);
}
__device__ __forceinline__ uint4 pk8(const float* e) {
    uint4 r; r.x = pk2(e[0],e[1]); r.y = pk2(e[2],e[3]);
    r.z = pk2(e[4],e[5]); r.w = pk2(e[6],e[7]); return r;
}

// async 16B/lane global->LDS
__device__ __forceinline__ void gload_lds16(const void* g, void* l) {
    __builtin_amdgcn_global_load_lds((__attribute__((address_space(1))) void*)g,
                                     (__attribute__((address_space(3))) void*)l, 16, 0, 0);
}

// hand-rolled grid barrier: monotonic counter, all GRID_CH blocks co-resident by construction.
// threadfence = device-scope (cross-XCD L2 wb/inv). Counter only grows -> replay-safe, no hang.
__device__ __forceinline__ void gbar(int* cnt, int target) {
    __threadfence();
    __syncthreads();
    if (threadIdx.x == 0) {
        atomicAdd(cnt, 1);
        while (atomicAdd(cnt, 0) < target) __builtin_amdgcn_s_sleep(2);
        __threadfence();
    }
    __syncthreads();
}

// ---- prep: convert+transpose weights to bf16 [kk][o][f]; zero GN partials + barrier counters ----
__global__ __launch_bounds__(256) void prep_k(
    const float* __restrict__ W1, const float* __restrict__ Wr, const float* __restrict__ W2,
    unsigned short* __restrict__ Wt1, unsigned short* __restrict__ Wtr, unsigned short* __restrict__ Wt2,
    float* __restrict__ part)   // zeroes 1024 floats: PART1, PART2, CNT1, CNT2, slack
{
    int i = blockIdx.x * 256 + threadIdx.x;
    if (i < 32768) {                 // Wt2[kk][o][f] = W2[kk][f][o], F=64
        int kk = i >> 12, rem = i & 4095, o = rem >> 6, f = rem & 63;
        Wt2[i] = f2us(W2[kk * 4096 + f * 64 + o]);
    } else if (i < 49152) {          // Wt1, F=32
        int j = i - 32768;
        int kk = j >> 11, rem = j & 2047, o = rem >> 5, f = rem & 31;
        Wt1[j] = f2us(W1[kk * 2048 + f * 64 + o]);
    } else if (i < 65536) {          // Wtr, F=32
        int j = i - 49152;
        int kk = j >> 11, rem = j & 2047, o = rem >> 5, f = rem & 31;
        Wtr[j] = f2us(Wr[kk * 2048 + f * 64 + o]);
    } else if (i < 66560) {
        part[i - 65536] = 0.f;
    }
}

// ---- conv1 fused chain: phase0 reorder(x)->T0, then 7 spmm steps with global barriers.
// Thread owns a 16-elem chunk of one row (tid = v*4+c). col/vals + T_{k-1}/T_{k-2} own-chunks
// live in registers the whole chain. ----
__global__ __launch_bounds__(256, 4) void chain1_k(
    const float* __restrict__ x, const float* __restrict__ vals, const int* __restrict__ col,
    unsigned short* __restrict__ TS, int* __restrict__ cnt)
{
    int tid = blockIdx.x * 256 + threadIdx.x;   // < V*4
    int v = tid >> 2, c = tid & 3;
    int base = v * NNZ;
    int cols[NNZ]; float ev[NNZ];
    #pragma unroll
    for (int n = 0; n < NNZ; ++n) {
        cols[n] = col[base + n] * 64 + c * 16;  // element offset of this chunk in any slot
        ev[n] = vals[base + n];
    }

    uint4 cur0, cur1, prev0, prev1;
    {   // phase 0: T0 = reorder(x); row layout [v][b*32+f]
        int b = c >> 1, f0 = (c & 1) * 16;
        const float* xp = x + ((size_t)b * V + v) * 32 + f0;
        float e[16];
        #pragma unroll
        for (int i = 0; i < 16; ++i) e[i] = xp[i];
        cur0 = pk8(e); cur1 = pk8(e + 8);
        uint4* dst = (uint4*)(void*)(TS + (size_t)v * 64 + c * 16);
        dst[0] = cur0; dst[1] = cur1;
    }

    #pragma unroll
    for (int k = 1; k < 8; ++k) {
        gbar(cnt, GRID_CH * k);                 // slot k-1 complete everywhere
        const unsigned short* zc = TS + (size_t)(k - 1) * V * 64;
        float t[16];
        #pragma unroll
        for (int i = 0; i < 16; ++i) t[i] = 0.f;
        #pragma unroll
        for (int n = 0; n < NNZ; ++n) {
            const uint4* p = (const uint4*)(const void*)(zc + cols[n]);
            uint4 u0 = p[0], u1 = p[1];
            float a = ev[n];
            float e[16];
            up8(u0, e); up8(u1, e + 8);
            #pragma unroll
            for (int i = 0; i < 16; ++i) t[i] += a * e[i];
        }
        if (k > 1) {
            float pv[16];
            up8(prev0, pv); up8(prev1, pv + 8);
            #pragma unroll
            for (int i = 0; i < 16; ++i) t[i] = 2.f * t[i] - pv[i];
        }
        uint4 n0 = pk8(t), n1 = pk8(t + 8);
        prev0 = cur0; prev1 = cur1; cur0 = n0; cur1 = n1;
        uint4* dst = (uint4*)(void*)(TS + ((size_t)k * V + v) * 64 + c * 16);
        dst[0] = n0; dst[1] = n1;
    }
}

// ---- conv2 fused chain: phase0 GN1(ACC)+LeakyReLU->T0, then 7 spmm steps. 32-elem chunks. ----
__global__ __launch_bounds__(256, 4) void chain2_k(
    const unsigned short* __restrict__ ACC, const float* __restrict__ part,
    const float* __restrict__ gam, const float* __restrict__ bet,
    const float* __restrict__ vals, const int* __restrict__ col,
    unsigned short* __restrict__ TS, int* __restrict__ cnt)
{
    int tid = blockIdx.x * 256 + threadIdx.x;   // < V*4
    int v = tid >> 2, c = tid & 3;
    int base = v * NNZ;
    int cols[NNZ]; float ev[NNZ];
    #pragma unroll
    for (int n = 0; n < NNZ; ++n) {
        cols[n] = col[base + n] * 128 + c * 32;
        ev[n] = vals[base + n];
    }

    uint4 cur[4], prev[4];
    {   // phase 0: GN1 + LeakyReLU from ACC[b][v][64] -> T0 row [v][b*64+o]
        int b = c >> 1, o0 = (c & 1) * 32;
        const float N = (float)V * 8.f;
        float e[32];
        const uint4* ap = (const uint4*)(const void*)(ACC + ((size_t)b * V + v) * 64 + o0);
        #pragma unroll
        for (int q = 0; q < 4; ++q) up8(ap[q], e + q * 8);
        #pragma unroll
        for (int q = 0; q < 4; ++q) {
            int j = b * 8 + ((o0 + q * 8) >> 3);
            float mu = part[j * 2] / N;
            float rs = rsqrtf(part[j * 2 + 1] / N - mu * mu + EPSV);
            #pragma unroll
            for (int i = 0; i < 8; ++i) {
                int o = o0 + q * 8 + i;
                float tt = (e[q * 8 + i] - mu) * rs * gam[o] + bet[o];
                e[q * 8 + i] = tt > 0.f ? tt : SLOPE * tt;
            }
        }
        #pragma unroll
        for (int q = 0; q < 4; ++q) cur[q] = pk8(e + q * 8);
        uint4* dst = (uint4*)(void*)(TS + (size_t)v * 128 + c * 32);
        #pragma unroll
        for (int q = 0; q < 4; ++q) dst[q] = cur[q];
    }

    #pragma unroll
    for (int k = 1; k < 8; ++k) {
        gbar(cnt, GRID_CH * k);
        const unsigned short* zc = TS + (size_t)(k - 1) * V * 128;
        float t[32];
        #pragma unroll
        for (int i = 0; i < 32; ++i) t[i] = 0.f;
        #pragma unroll
        for (int n = 0; n < NNZ; ++n) {
            const uint4* p = (const uint4*)(const void*)(zc + cols[n]);
            float a = ev[n];
            #pragma unroll
            for (int q = 0; q < 4; ++q) {
                float e[8];
                up8(p[q], e);
                #pragma unroll
                for (int i = 0; i < 8; ++i) t[q * 8 + i] += a * e[i];
            }
        }
        if (k > 1) {
            #pragma unroll
            for (int q = 0; q < 4; ++q) {
                float pv[8];
                up8(prev[q], pv);
                #pragma unroll
                for (int i = 0; i < 8; ++i) t[q * 8 + i] = 2.f * t[q * 8 + i] - pv[i];
            }
        }
        uint4 nn[4];
        #pragma unroll
        for (int q = 0; q < 4; ++q) { nn[q] = pk8(t + q * 8); prev[q] = cur[q]; cur[q] = nn[q]; }
        uint4* dst = (uint4*)(void*)(TS + ((size_t)k * V + v) * 128 + c * 32);
        #pragma unroll
        for (int q = 0; q < 4; ++q) dst[q] = nn[q];
    }
}

// ---- MFMA GEMM (R11-proven): 64-row tile, NPH staging phases, B in VGPRs,
// ds_read_b128+MFMA inner loop, LDS-transposed coalesced epilogue + GN partials ----
template<int F, int NKK, int NPH, bool DUAL, bool INIT, bool FINAL>
__global__ __launch_bounds__(256) void mfma_gemm(
    const unsigned short* __restrict__ T,
    const unsigned short* __restrict__ WtA, const unsigned short* __restrict__ WtB,
    const float* __restrict__ biasA, const float* __restrict__ biasB,
    unsigned short* __restrict__ ACC, float* __restrict__ resOut,
    float* __restrict__ part)
{
    constexpr int KPP = NKK / NPH;
    constexpr int CPR = F / 4;
    constexpr int FH = F / 32;
    constexpr int RST = 68;
    constexpr int STAGE_SH = KPP * 64 * 2 * F;
    constexpr int TRANS_SH = (DUAL ? 2 : 1) * 2 * 64 * RST * 2;
    constexpr int SH = STAGE_SH > TRANS_SH ? STAGE_SH : TRANS_SH;
    __shared__ unsigned short shraw[SH];
    __shared__ float sGrp[32];

    unsigned short* tile = shraw;
    float* accbuf  = (float*)shraw;
    float* dualbuf = accbuf + 2 * 64 * RST;

    int wv = threadIdx.x >> 6, lane = threadIdx.x & 63;
    int quad = lane >> 4, l15 = lane & 15;
    int v0 = blockIdx.x * 64;
    int ot = wv;

    bf16x8 bw[NKK][FH];
    bf16x8 bd[NKK][FH];
    f32x4 acc[4][2];
    f32x4 accd[4][2];

    #pragma unroll
    for (int ph = 0; ph < NPH; ++ph) {
        if (ph > 0) __syncthreads();
        #pragma unroll
        for (int i = 0; i < (KPP * 64 * CPR) / 256; ++i) {
            int s = (i * 4 + wv) * 64 + lane;
            int kkl = s / (64 * CPR);
            int ws = s - kkl * 64 * CPR;
            int row = ws / CPR;
            int cl = ws - row * CPR;
            int cg2 = (cl & ~7) | ((cl & 7) ^ (row & 7));
            const unsigned short* gp =
                T + ((size_t)(ph * KPP + kkl) * V + v0 + row) * (2 * F) + cg2 * 8;
            gload_lds16(gp, tile + (size_t)(i * 4 + wv) * 64 * 8);
        }
        if (ph == 0) {
            #pragma unroll
            for (int kk = 0; kk < NKK; ++kk)
                #pragma unroll
                for (int fh = 0; fh < FH; ++fh) {
                    size_t brow = ((size_t)kk * 64 + ot * 16 + l15) * F + fh * 32 + quad * 8;
                    bw[kk][fh] = *(const bf16x8*)(const void*)(WtA + brow);
                    if constexpr (DUAL) bd[kk][fh] = *(const bf16x8*)(const void*)(WtB + brow);
                }
            #pragma unroll
            for (int m = 0; m < 4; ++m)
                #pragma unroll
                for (int b = 0; b < 2; ++b) {
                    acc[m][b] = (f32x4){0.f, 0.f, 0.f, 0.f};
                    if constexpr (DUAL) accd[m][b] = (f32x4){0.f, 0.f, 0.f, 0.f};
                }
        }
        __syncthreads();
        #pragma unroll
        for (int kkl = 0; kkl < KPP; ++kkl) {
            int kk = ph * KPP + kkl;
            #pragma unroll
            for (int fh = 0; fh < FH; ++fh) {
                #pragma unroll
                for (int m = 0; m < 4; ++m) {
                    int r = m * 16 + l15;
                    int rx = r & 7;
                    const unsigned short* rbase = tile + ((size_t)kkl * 64 + r) * 2 * F;
                    #pragma unroll
                    for (int b = 0; b < 2; ++b) {
                        int c0 = b * (CPR / 2) + fh * 4 + quad;
                        int s0 = (c0 & ~7) | ((c0 & 7) ^ rx);
                        bf16x8 a = *(const bf16x8*)(const void*)(rbase + s0 * 8);
                        acc[m][b] = __builtin_amdgcn_mfma_f32_16x16x32_bf16(a, bw[kk][fh], acc[m][b], 0, 0, 0);
                        if constexpr (DUAL)
                            accd[m][b] = __builtin_amdgcn_mfma_f32_16x16x32_bf16(a, bd[kk][fh], accd[m][b], 0, 0, 0);
                    }
                }
            }
        }
    }

    __syncthreads();
    int o = ot * 16 + l15;
    float bia = FINAL ? biasA[o] : 0.f;
    float biaB = DUAL ? biasB[o] : 0.f;
    #pragma unroll
    for (int m = 0; m < 4; ++m)
        #pragma unroll
        for (int b = 0; b < 2; ++b)
            #pragma unroll
            for (int rr = 0; rr < 4; ++rr) {
                int r = m * 16 + quad * 4 + rr;
                accbuf[(b * 64 + r) * RST + o] = acc[m][b][rr] + bia;
                if constexpr (DUAL) dualbuf[(b * 64 + r) * RST + o] = accd[m][b][rr] + biaB;
            }
    if constexpr (FINAL) {
        if (threadIdx.x < 32) sGrp[threadIdx.x] = 0.f;
    }
    __syncthreads();

    #pragma unroll
    for (int j = 0; j < 4; ++j) {
        int cid = threadIdx.x + 256 * j;
        int g = cid & 7, r = (cid >> 3) & 63, b = cid >> 9;
        int o0 = g * 8;
        const float* src = accbuf + (b * 64 + r) * RST + o0;
        float e[8];
        #pragma unroll
        for (int i = 0; i < 8; ++i) e[i] = src[i];
        size_t gidx = ((size_t)b * V + v0 + r) * 64 + o0;
        if constexpr (!INIT) {
            uint4 old = *(const uint4*)(const void*)(ACC + gidx);
            e[0] += lo2f(old.x); e[1] += hi2f(old.x);
            e[2] += lo2f(old.y); e[3] += hi2f(old.y);
            e[4] += lo2f(old.z); e[5] += hi2f(old.z);
            e[6] += lo2f(old.w); e[7] += hi2f(old.w);
        }
        uint4 pk;
        pk.x = pk2(e[0], e[1]); pk.y = pk2(e[2], e[3]);
        pk.z = pk2(e[4], e[5]); pk.w = pk2(e[6], e[7]);
        *(uint4*)(void*)(ACC + gidx) = pk;
        if constexpr (FINAL) {
            float s = 0.f, q = 0.f;
            #pragma unroll
            for (int i = 0; i < 8; ++i) { s += e[i]; q += e[i] * e[i]; }
            atomicAdd(&sGrp[b * 8 + g], s);
            atomicAdd(&sGrp[16 + b * 8 + g], q);
        }
    }
    if constexpr (DUAL) {
        #pragma unroll
        for (int j = 0; j < 8; ++j) {
            int cid = threadIdx.x + 256 * j;
            int oc = cid & 15, r = (cid >> 4) & 63, b = cid >> 10;
            float4 vv = *(const float4*)(const void*)(dualbuf + (b * 64 + r) * RST + oc * 4);
            *(float4*)(void*)(resOut + ((size_t)b * V + v0 + r) * 64 + oc * 4) = vv;
        }
    }
    if constexpr (FINAL) {
        __syncthreads();
        if (threadIdx.x < 16) {
            atomicAdd(&part[threadIdx.x * 2],     sGrp[threadIdx.x]);
            atomicAdd(&part[threadIdx.x * 2 + 1], sGrp[16 + threadIdx.x]);
        }
    }
}

// ---- final (stats inline): out[b][v][o] (holds res) += LeakyReLU(GN2(ACC)) ----
__global__ __launch_bounds__(256) void final_out(const unsigned short* __restrict__ ACC,
                                                 float* outres,
                                                 const float* __restrict__ part,
                                                 const float* __restrict__ gamma, const float* __restrict__ beta) {
    int idx = blockIdx.x * 256 + threadIdx.x;   // < 2*V*8 (8-channel chunks)
    int b = idx >= V * 8 ? 1 : 0;
    int r = idx - b * V * 8;
    int v = r >> 3, g = r & 7;
    int j = b * 8 + g;
    const float N = (float)V * 8.f;
    float mean = part[j * 2] / N;
    float rstd = rsqrtf(part[j * 2 + 1] / N - mean * mean + EPSV);
    int o0 = g * 8;
    size_t base = ((size_t)b * V + v) * 64 + o0;
    uint4 aa = *(const uint4*)(const void*)(ACC + base);
    float e[8];
    up8(aa, e);
    float4 r0 = *(const float4*)(const void*)(outres + base);
    float4 r1 = *(const float4*)(const void*)(outres + base + 4);
    float y[8];
    #pragma unroll
    for (int i = 0; i < 8; ++i) {
        float t = (e[i] - mean) * rstd * gamma[o0 + i] + beta[o0 + i];
        y[i] = t > 0.f ? t : SLOPE * t;
    }
    float4 w0 = { y[0] + r0.x, y[1] + r0.y, y[2] + r0.z, y[3] + r0.w };
    float4 w1 = { y[4] + r1.x, y[5] + r1.y, y[6] + r1.z, y[7] + r1.w };
    *(float4*)(void*)(outres + base) = w0;
    *(float4*)(void*)(outres + base + 4) = w1;
}

extern "C" void kernel_launch(void* const* d_in, const int* in_sizes, int n_in,
                              void* d_out, int out_size, void* d_ws, size_t ws_size,
                              hipStream_t stream) {
    const float* x    = (const float*)d_in[0];
    const float* vals = (const float*)d_in[1];
    const int*   col  = (const int*)d_in[3];
    const float* W1   = (const float*)d_in[4];
    const float* b1   = (const float*)d_in[5];
    const float* g1   = (const float*)d_in[6];
    const float* be1  = (const float*)d_in[7];
    const float* W2   = (const float*)d_in[8];
    const float* b2   = (const float*)d_in[9];
    const float* g2   = (const float*)d_in[10];
    const float* be2  = (const float*)d_in[11];
    const float* Wr   = (const float*)d_in[12];
    const float* br   = (const float*)d_in[13];
    float* out = (float*)d_out;

    // workspace: TS bf16 8*[V][128] 100.7MB | ACC bf16 [2][V][64] | Wt1/Wtr/Wt2 | PART1/PART2/CNT1/CNT2
    unsigned short* TS  = (unsigned short*)d_ws;
    unsigned short* ACC = TS + (size_t)8 * V * 128;
    unsigned short* Wt1 = ACC + (size_t)2 * V * 64;
    unsigned short* Wtr = Wt1 + 8 * 64 * 32;
    unsigned short* Wt2 = Wtr + 8 * 64 * 32;
    float* PART1 = (float*)(Wt2 + 8 * 64 * 64);
    float* PART2 = PART1 + 32;
    int*   CNT1  = (int*)(PART2 + 32);
    int*   CNT2  = CNT1 + 1;        // both inside the 1024-float region prep zeroes

    prep_k<<<260, 256, 0, stream>>>(W1, Wr, W2, Wt1, Wtr, Wt2, PART1);

    // conv1 fused chain: reorder + 7 spmm steps, hand-rolled grid barrier
    chain1_k<<<GRID_CH, 256, 0, stream>>>(x, vals, col, TS, CNT1);

    // conv1 + res GEMM over all 8 T_k
    mfma_gemm<32, 8, 1, true, true, true><<<V / 64, 256, 0, stream>>>(
        TS, Wt1, Wtr, b1, br, ACC, out, PART1);

    // conv2 fused chain: GN1-apply + 7 spmm steps
    chain2_k<<<GRID_CH, 256, 0, stream>>>(ACC, PART1, g1, be1, vals, col, TS, CNT2);

    // conv2: single GEMM, two staging phases
    mfma_gemm<64, 8, 2, false, true, true><<<V / 64, 256, 0, stream>>>(
        TS, Wt2, nullptr, b2, nullptr, ACC, nullptr, PART2);

    final_out<<<2 * V * 8 / 256, 256, 0, stream>>>(ACC, out, PART2, g2, be2);
}

// Round 14
// 385.680 us; speedup vs baseline: 7.5060x; 7.5060x over previous
//
#include <hip/hip_runtime.h>
#include <hip/hip_bf16.h>

#define V 49152
#define NNZ 9
#define EPSV 1e-5f
#define SLOPE 0.1f

typedef __attribute__((ext_vector_type(8))) short bf16x8;   // 8 bf16 (4 VGPRs)
typedef __attribute__((ext_vector_type(4))) float f32x4;    // MFMA C/D

__device__ __forceinline__ float lo2f(unsigned u) { return __uint_as_float(u << 16); }
__device__ __forceinline__ float hi2f(unsigned u) { return __uint_as_float(u & 0xffff0000u); }
__device__ __forceinline__ unsigned short f2us(float f) {
    __hip_bfloat16 h = __float2bfloat16(f);
    return *(unsigned short*)&h;
}
__device__ __forceinline__ float us2f(unsigned short u) { return __uint_as_float(((unsigned)u) << 16); }
__device__ __forceinline__ unsigned pk2(float a, float b) {
    return ((unsigned)f2us(a)) | (((unsigned)f2us(b)) << 16);
}
__device__ __forceinline__ void up8(uint4 u, float* e) {
    e[0]=lo2f(u.x); e[1]=hi2f(u.x); e[2]=lo2f(u.y); e[3]=hi2f(u.y);
    e[4]=lo2f(u.z); e[5]=hi2f(u.z); e[6]=lo2f(u.w); e[7]=hi2f(u.w);
}
__device__ __forceinline__ uint4 pk8(const float* e) {
    uint4 r; r.x = pk2(e[0],e[1]); r.y = pk2(e[2],e[3]);
    r.z = pk2(e[4],e[5]); r.w = pk2(e[6],e[7]); return r;
}

// async 16B/lane global->LDS
__device__ __forceinline__ void gload_lds16(const void* g, void* l) {
    __builtin_amdgcn_global_load_lds((__attribute__((address_space(1))) void*)g,
                                     (__attribute__((address_space(3))) void*)l, 16, 0, 0);
}

// ---- prep: convert+transpose weights to bf16 [kk][o][f]; zero GN partial buffers ----
__global__ __launch_bounds__(256) void prep_k(
    const float* __restrict__ W1, const float* __restrict__ Wr, const float* __restrict__ W2,
    unsigned short* __restrict__ Wt1, unsigned short* __restrict__ Wtr, unsigned short* __restrict__ Wt2,
    float* __restrict__ part)
{
    int i = blockIdx.x * 256 + threadIdx.x;
    if (i < 32768) {                 // Wt2[kk][o][f] = W2[kk][f][o], F=64
        int kk = i >> 12, rem = i & 4095, o = rem >> 6, f = rem & 63;
        Wt2[i] = f2us(W2[kk * 4096 + f * 64 + o]);
    } else if (i < 49152) {          // Wt1, F=32
        int j = i - 32768;
        int kk = j >> 11, rem = j & 2047, o = rem >> 5, f = rem & 31;
        Wt1[j] = f2us(W1[kk * 2048 + f * 64 + o]);
    } else if (i < 65536) {          // Wtr, F=32
        int j = i - 49152;
        int kk = j >> 11, rem = j & 2047, o = rem >> 5, f = rem & 31;
        Wtr[j] = f2us(Wr[kk * 2048 + f * 64 + o]);
    } else if (i < 66560) {
        part[i - 65536] = 0.f;
    }
}

// ---- conv1 fused step 0+1: T0 = reorder(x), T1 = L @ reorder(x), gathering x (fp32) directly.
// Thread owns an 8-elem chunk: tid = v*8 + c; b = c>>2, f0 = (c&3)*8. ----
__global__ __launch_bounds__(256) void ch1_step01(
    const float* __restrict__ x, const float* __restrict__ vals, const int* __restrict__ col,
    unsigned short* __restrict__ TS)
{
    int tid = blockIdx.x * 256 + threadIdx.x;   // < V*8
    int v = tid >> 3, c = tid & 7;
    int b = c >> 2, f0 = (c & 3) * 8;
    int base = v * NNZ;

    float t[8] = {0.f,0.f,0.f,0.f,0.f,0.f,0.f,0.f};
    #pragma unroll
    for (int n = 0; n < NNZ; ++n) {
        float a = vals[base + n];
        int cc = col[base + n];
        const float4* p = (const float4*)(const void*)(x + ((size_t)b * V + cc) * 32 + f0);
        float4 u0 = p[0], u1 = p[1];
        t[0] += a * u0.x; t[1] += a * u0.y; t[2] += a * u0.z; t[3] += a * u0.w;
        t[4] += a * u1.x; t[5] += a * u1.y; t[6] += a * u1.z; t[7] += a * u1.w;
    }
    // own row chunk -> T0
    {
        const float4* p = (const float4*)(const void*)(x + ((size_t)b * V + v) * 32 + f0);
        float4 u0 = p[0], u1 = p[1];
        float e[8] = { u0.x, u0.y, u0.z, u0.w, u1.x, u1.y, u1.z, u1.w };
        *(uint4*)(void*)(TS + (size_t)v * 64 + c * 8) = pk8(e);
    }
    *(uint4*)(void*)(TS + ((size_t)V + v) * 64 + c * 8) = pk8(t);
}

// ---- conv2 fused step 0+1: h1 = LeakyReLU(GN1(ACC)) elementwise; T0 = h1, T1 = L @ h1,
// gathering ACC directly and applying y = leaky(A*val + B) per gathered element.
// Thread owns a 16-elem chunk: tid = v*8 + c; b = c>>2, o0 = (c&3)*16 (2 GN groups). ----
__global__ __launch_bounds__(256) void ch2_step01(
    const unsigned short* __restrict__ ACC, const float* __restrict__ part,
    const float* __restrict__ gam, const float* __restrict__ bet,
    const float* __restrict__ vals, const int* __restrict__ col,
    unsigned short* __restrict__ TS)
{
    int tid = blockIdx.x * 256 + threadIdx.x;   // < V*8
    int v = tid >> 3, c = tid & 7;
    int b = c >> 2, o0 = (c & 3) * 16;
    int base = v * NNZ;
    const float N = (float)V * 8.f;

    // per-channel affine: y_pre = A[i]*val + B[i]
    float A[16], Bc[16];
    #pragma unroll
    for (int q = 0; q < 2; ++q) {
        int j = b * 8 + (o0 >> 3) + q;
        float mu = part[j * 2] / N;
        float rs = rsqrtf(part[j * 2 + 1] / N - mu * mu + EPSV);
        #pragma unroll
        for (int i = 0; i < 8; ++i) {
            int o = o0 + q * 8 + i;
            float g = gam[o] * rs;
            A[q * 8 + i] = g;
            Bc[q * 8 + i] = bet[o] - mu * g;
        }
    }

    float t[16];
    #pragma unroll
    for (int i = 0; i < 16; ++i) t[i] = 0.f;
    #pragma unroll
    for (int n = 0; n < NNZ; ++n) {
        float a = vals[base + n];
        int cc = col[base + n];
        const uint4* p = (const uint4*)(const void*)(ACC + ((size_t)b * V + cc) * 64 + o0);
        uint4 u0 = p[0], u1 = p[1];
        float e[16];
        up8(u0, e); up8(u1, e + 8);
        #pragma unroll
        for (int i = 0; i < 16; ++i) {
            float y = A[i] * e[i] + Bc[i];
            y = y > 0.f ? y : SLOPE * y;
            t[i] += a * y;
        }
    }
    // own row chunk -> T0 = h1
    {
        const uint4* p = (const uint4*)(const void*)(ACC + ((size_t)b * V + v) * 64 + o0);
        uint4 u0 = p[0], u1 = p[1];
        float e[16];
        up8(u0, e); up8(u1, e + 8);
        #pragma unroll
        for (int i = 0; i < 16; ++i) {
            float y = A[i] * e[i] + Bc[i];
            e[i] = y > 0.f ? y : SLOPE * y;
        }
        uint4* dst = (uint4*)(void*)(TS + (size_t)v * 128 + c * 16);
        dst[0] = pk8(e); dst[1] = pk8(e + 8);
    }
    uint4* dst = (uint4*)(void*)(TS + ((size_t)V + v) * 128 + c * 16);
    dst[0] = pk8(t); dst[1] = pk8(t + 8);
}

// ---- SpMM Chebyshev step: zn = 2*(L@zc) - zp (bf16 rows). 32B (2 uint4) per thread. ----
template<int THR, bool FIRST>
__global__ __launch_bounds__(256) void spmm_step(
    const uint4* __restrict__ zc, const uint4* __restrict__ zp, uint4* __restrict__ zn,
    const float* __restrict__ vals, const int* __restrict__ col)
{
    constexpr int L4 = THR * 2;                   // uint4 per row
    int tid = blockIdx.x * 256 + threadIdx.x;     // over V*THR
    int v = tid / THR;
    int c = (tid - v * THR) * 2;
    int base = v * NNZ;
    float t[16];
    #pragma unroll
    for (int i = 0; i < 16; ++i) t[i] = 0.f;
    #pragma unroll
    for (int n = 0; n < NNZ; ++n) {
        float a = vals[base + n];
        int cc = col[base + n];
        const uint4* p = zc + (size_t)cc * L4 + c;
        uint4 u0 = p[0];
        uint4 u1 = p[1];
        t[0] += a * lo2f(u0.x); t[1] += a * hi2f(u0.x);
        t[2] += a * lo2f(u0.y); t[3] += a * hi2f(u0.y);
        t[4] += a * lo2f(u0.z); t[5] += a * hi2f(u0.z);
        t[6] += a * lo2f(u0.w); t[7] += a * hi2f(u0.w);
        t[8]  += a * lo2f(u1.x); t[9]  += a * hi2f(u1.x);
        t[10] += a * lo2f(u1.y); t[11] += a * hi2f(u1.y);
        t[12] += a * lo2f(u1.z); t[13] += a * hi2f(u1.z);
        t[14] += a * lo2f(u1.w); t[15] += a * hi2f(u1.w);
    }
    if (!FIRST) {
        const uint4* pp = zp + (size_t)v * L4 + c;
        uint4 p0 = pp[0];
        uint4 p1 = pp[1];
        t[0] = 2.f*t[0] - lo2f(p0.x); t[1] = 2.f*t[1] - hi2f(p0.x);
        t[2] = 2.f*t[2] - lo2f(p0.y); t[3] = 2.f*t[3] - hi2f(p0.y);
        t[4] = 2.f*t[4] - lo2f(p0.z); t[5] = 2.f*t[5] - hi2f(p0.z);
        t[6] = 2.f*t[6] - lo2f(p0.w); t[7] = 2.f*t[7] - hi2f(p0.w);
        t[8]  = 2.f*t[8]  - lo2f(p1.x); t[9]  = 2.f*t[9]  - hi2f(p1.x);
        t[10] = 2.f*t[10] - lo2f(p1.y); t[11] = 2.f*t[11] - hi2f(p1.y);
        t[12] = 2.f*t[12] - lo2f(p1.z); t[13] = 2.f*t[13] - hi2f(p1.z);
        t[14] = 2.f*t[14] - lo2f(p1.w); t[15] = 2.f*t[15] - hi2f(p1.w);
    }
    uint4 r0, r1;
    r0.x = pk2(t[0], t[1]);  r0.y = pk2(t[2], t[3]);
    r0.z = pk2(t[4], t[5]);  r0.w = pk2(t[6], t[7]);
    r1.x = pk2(t[8], t[9]);  r1.y = pk2(t[10], t[11]);
    r1.z = pk2(t[12], t[13]); r1.w = pk2(t[14], t[15]);
    uint4* q = zn + (size_t)v * L4 + c;
    q[0] = r0;
    q[1] = r1;
}

// ---- MFMA GEMM (R11-proven): 64-row tile, NPH staging phases, B in VGPRs,
// ds_read_b128+MFMA inner loop, LDS-transposed coalesced epilogue + GN partials ----
template<int F, int NKK, int NPH, bool DUAL, bool INIT, bool FINAL>
__global__ __launch_bounds__(256) void mfma_gemm(
    const unsigned short* __restrict__ T,
    const unsigned short* __restrict__ WtA, const unsigned short* __restrict__ WtB,
    const float* __restrict__ biasA, const float* __restrict__ biasB,
    unsigned short* __restrict__ ACC, float* __restrict__ resOut,
    float* __restrict__ part)
{
    constexpr int KPP = NKK / NPH;
    constexpr int CPR = F / 4;
    constexpr int FH = F / 32;
    constexpr int RST = 68;
    constexpr int STAGE_SH = KPP * 64 * 2 * F;
    constexpr int TRANS_SH = (DUAL ? 2 : 1) * 2 * 64 * RST * 2;
    constexpr int SH = STAGE_SH > TRANS_SH ? STAGE_SH : TRANS_SH;
    __shared__ unsigned short shraw[SH];
    __shared__ float sGrp[32];

    unsigned short* tile = shraw;
    float* accbuf  = (float*)shraw;
    float* dualbuf = accbuf + 2 * 64 * RST;

    int wv = threadIdx.x >> 6, lane = threadIdx.x & 63;
    int quad = lane >> 4, l15 = lane & 15;
    int v0 = blockIdx.x * 64;
    int ot = wv;

    bf16x8 bw[NKK][FH];
    bf16x8 bd[NKK][FH];
    f32x4 acc[4][2];
    f32x4 accd[4][2];

    #pragma unroll
    for (int ph = 0; ph < NPH; ++ph) {
        if (ph > 0) __syncthreads();
        #pragma unroll
        for (int i = 0; i < (KPP * 64 * CPR) / 256; ++i) {
            int s = (i * 4 + wv) * 64 + lane;
            int kkl = s / (64 * CPR);
            int ws = s - kkl * 64 * CPR;
            int row = ws / CPR;
            int cl = ws - row * CPR;
            int cg2 = (cl & ~7) | ((cl & 7) ^ (row & 7));
            const unsigned short* gp =
                T + ((size_t)(ph * KPP + kkl) * V + v0 + row) * (2 * F) + cg2 * 8;
            gload_lds16(gp, tile + (size_t)(i * 4 + wv) * 64 * 8);
        }
        if (ph == 0) {
            #pragma unroll
            for (int kk = 0; kk < NKK; ++kk)
                #pragma unroll
                for (int fh = 0; fh < FH; ++fh) {
                    size_t brow = ((size_t)kk * 64 + ot * 16 + l15) * F + fh * 32 + quad * 8;
                    bw[kk][fh] = *(const bf16x8*)(const void*)(WtA + brow);
                    if constexpr (DUAL) bd[kk][fh] = *(const bf16x8*)(const void*)(WtB + brow);
                }
            #pragma unroll
            for (int m = 0; m < 4; ++m)
                #pragma unroll
                for (int b = 0; b < 2; ++b) {
                    acc[m][b] = (f32x4){0.f, 0.f, 0.f, 0.f};
                    if constexpr (DUAL) accd[m][b] = (f32x4){0.f, 0.f, 0.f, 0.f};
                }
        }
        __syncthreads();
        #pragma unroll
        for (int kkl = 0; kkl < KPP; ++kkl) {
            int kk = ph * KPP + kkl;
            #pragma unroll
            for (int fh = 0; fh < FH; ++fh) {
                #pragma unroll
                for (int m = 0; m < 4; ++m) {
                    int r = m * 16 + l15;
                    int rx = r & 7;
                    const unsigned short* rbase = tile + ((size_t)kkl * 64 + r) * 2 * F;
                    #pragma unroll
                    for (int b = 0; b < 2; ++b) {
                        int c0 = b * (CPR / 2) + fh * 4 + quad;
                        int s0 = (c0 & ~7) | ((c0 & 7) ^ rx);
                        bf16x8 a = *(const bf16x8*)(const void*)(rbase + s0 * 8);
                        acc[m][b] = __builtin_amdgcn_mfma_f32_16x16x32_bf16(a, bw[kk][fh], acc[m][b], 0, 0, 0);
                        if constexpr (DUAL)
                            accd[m][b] = __builtin_amdgcn_mfma_f32_16x16x32_bf16(a, bd[kk][fh], accd[m][b], 0, 0, 0);
                    }
                }
            }
        }
    }

    __syncthreads();
    int o = ot * 16 + l15;
    float bia = FINAL ? biasA[o] : 0.f;
    float biaB = DUAL ? biasB[o] : 0.f;
    #pragma unroll
    for (int m = 0; m < 4; ++m)
        #pragma unroll
        for (int b = 0; b < 2; ++b)
            #pragma unroll
            for (int rr = 0; rr < 4; ++rr) {
                int r = m * 16 + quad * 4 + rr;
                accbuf[(b * 64 + r) * RST + o] = acc[m][b][rr] + bia;
                if constexpr (DUAL) dualbuf[(b * 64 + r) * RST + o] = accd[m][b][rr] + biaB;
            }
    if constexpr (FINAL) {
        if (threadIdx.x < 32) sGrp[threadIdx.x] = 0.f;
    }
    __syncthreads();

    #pragma unroll
    for (int j = 0; j < 4; ++j) {
        int cid = threadIdx.x + 256 * j;
        int g = cid & 7, r = (cid >> 3) & 63, b = cid >> 9;
        int o0 = g * 8;
        const float* src = accbuf + (b * 64 + r) * RST + o0;
        float e[8];
        #pragma unroll
        for (int i = 0; i < 8; ++i) e[i] = src[i];
        size_t gidx = ((size_t)b * V + v0 + r) * 64 + o0;
        if constexpr (!INIT) {
            uint4 old = *(const uint4*)(const void*)(ACC + gidx);
            e[0] += lo2f(old.x); e[1] += hi2f(old.x);
            e[2] += lo2f(old.y); e[3] += hi2f(old.y);
            e[4] += lo2f(old.z); e[5] += hi2f(old.z);
            e[6] += lo2f(old.w); e[7] += hi2f(old.w);
        }
        uint4 pk;
        pk.x = pk2(e[0], e[1]); pk.y = pk2(e[2], e[3]);
        pk.z = pk2(e[4], e[5]); pk.w = pk2(e[6], e[7]);
        *(uint4*)(void*)(ACC + gidx) = pk;
        if constexpr (FINAL) {
            float s = 0.f, q = 0.f;
            #pragma unroll
            for (int i = 0; i < 8; ++i) { s += e[i]; q += e[i] * e[i]; }
            atomicAdd(&sGrp[b * 8 + g], s);
            atomicAdd(&sGrp[16 + b * 8 + g], q);
        }
    }
    if constexpr (DUAL) {
        #pragma unroll
        for (int j = 0; j < 8; ++j) {
            int cid = threadIdx.x + 256 * j;
            int oc = cid & 15, r = (cid >> 4) & 63, b = cid >> 10;
            float4 vv = *(const float4*)(const void*)(dualbuf + (b * 64 + r) * RST + oc * 4);
            *(float4*)(void*)(resOut + ((size_t)b * V + v0 + r) * 64 + oc * 4) = vv;
        }
    }
    if constexpr (FINAL) {
        __syncthreads();
        if (threadIdx.x < 16) {
            atomicAdd(&part[threadIdx.x * 2],     sGrp[threadIdx.x]);
            atomicAdd(&part[threadIdx.x * 2 + 1], sGrp[16 + threadIdx.x]);
        }
    }
}

// ---- final (stats inline): out[b][v][o] (holds res) += LeakyReLU(GN2(ACC)) ----
__global__ __launch_bounds__(256) void final_out(const unsigned short* __restrict__ ACC,
                                                 float* outres,
                                                 const float* __restrict__ part,
                                                 const float* __restrict__ gamma, const float* __restrict__ beta) {
    int idx = blockIdx.x * 256 + threadIdx.x;   // < 2*V*8 (8-channel chunks)
    int b = idx >= V * 8 ? 1 : 0;
    int r = idx - b * V * 8;
    int v = r >> 3, g = r & 7;
    int j = b * 8 + g;
    const float N = (float)V * 8.f;
    float mean = part[j * 2] / N;
    float rstd = rsqrtf(part[j * 2 + 1] / N - mean * mean + EPSV);
    int o0 = g * 8;
    size_t base = ((size_t)b * V + v) * 64 + o0;
    uint4 aa = *(const uint4*)(const void*)(ACC + base);
    float e[8];
    up8(aa, e);
    float4 r0 = *(const float4*)(const void*)(outres + base);
    float4 r1 = *(const float4*)(const void*)(outres + base + 4);
    float y[8];
    #pragma unroll
    for (int i = 0; i < 8; ++i) {
        float t = (e[i] - mean) * rstd * gamma[o0 + i] + beta[o0 + i];
        y[i] = t > 0.f ? t : SLOPE * t;
    }
    float4 w0 = { y[0] + r0.x, y[1] + r0.y, y[2] + r0.z, y[3] + r0.w };
    float4 w1 = { y[4] + r1.x, y[5] + r1.y, y[6] + r1.z, y[7] + r1.w };
    *(float4*)(void*)(outres + base) = w0;
    *(float4*)(void*)(outres + base + 4) = w1;
}

extern "C" void kernel_launch(void* const* d_in, const int* in_sizes, int n_in,
                              void* d_out, int out_size, void* d_ws, size_t ws_size,
                              hipStream_t stream) {
    const float* x    = (const float*)d_in[0];
    const float* vals = (const float*)d_in[1];
    const int*   col  = (const int*)d_in[3];
    const float* W1   = (const float*)d_in[4];
    const float* b1   = (const float*)d_in[5];
    const float* g1   = (const float*)d_in[6];
    const float* be1  = (const float*)d_in[7];
    const float* W2   = (const float*)d_in[8];
    const float* b2   = (const float*)d_in[9];
    const float* g2   = (const float*)d_in[10];
    const float* be2  = (const float*)d_in[11];
    const float* Wr   = (const float*)d_in[12];
    const float* br   = (const float*)d_in[13];
    float* out = (float*)d_out;

    // workspace: TS bf16 8*[V][128] 100.7MB | ACC bf16 [2][V][64] | Wt1/Wtr/Wt2 | PART1/PART2
    unsigned short* TS  = (unsigned short*)d_ws;
    unsigned short* ACC = TS + (size_t)8 * V * 128;
    unsigned short* Wt1 = ACC + (size_t)2 * V * 64;
    unsigned short* Wtr = Wt1 + 8 * 64 * 32;
    unsigned short* Wt2 = Wtr + 8 * 64 * 32;
    float* PART1 = (float*)(Wt2 + 8 * 64 * 64);
    float* PART2 = PART1 + 32;

    prep_k<<<260, 256, 0, stream>>>(W1, Wr, W2, Wt1, Wtr, Wt2, PART1);

    // ---- conv1 basis: fused reorder+step1 writes T0,T1; then 6 spmm steps ----
    uint4* T1s[8];
    for (int k = 0; k < 8; ++k) T1s[k] = (uint4*)(TS + (size_t)k * V * 64);

    ch1_step01<<<V * 8 / 256, 256, 0, stream>>>(x, vals, col, TS);
    for (int k = 2; k < 8; ++k)
        spmm_step<4, false><<<V * 4 / 256, 256, 0, stream>>>(T1s[k-1], T1s[k-2], T1s[k], vals, col);

    // conv1 + res GEMM over all 8 T_k
    mfma_gemm<32, 8, 1, true, true, true><<<V / 64, 256, 0, stream>>>(
        TS, Wt1, Wtr, b1, br, ACC, out, PART1);

    // ---- conv2: fused GN1+step1 writes T0,T1; then 6 spmm steps ----
    uint4* T2s[8];
    for (int k = 0; k < 8; ++k) T2s[k] = (uint4*)(TS + (size_t)k * V * 128);

    ch2_step01<<<V * 8 / 256, 256, 0, stream>>>(ACC, PART1, g1, be1, vals, col, TS);
    for (int k = 2; k < 8; ++k)
        spmm_step<8, false><<<V * 8 / 256, 256, 0, stream>>>(T2s[k-1], T2s[k-2], T2s[k], vals, col);

    // conv2: single GEMM, two staging phases
    mfma_gemm<64, 8, 2, false, true, true><<<V / 64, 256, 0, stream>>>(
        TS, Wt2, nullptr, b2, nullptr, ACC, nullptr, PART2);

    final_out<<<2 * V * 8 / 256, 256, 0, stream>>>(ACC, out, PART2, g2, be2);
}

// Round 15
// 366.781 us; speedup vs baseline: 7.8928x; 1.0515x over previous
//
#include <hip/hip_runtime.h>
#include <hip/hip_bf16.h>

#define V 49152
#define NNZ 9
#define EPSV 1e-5f
#define SLOPE 0.1f

typedef __attribute__((ext_vector_type(8))) short bf16x8;   // 8 bf16 (4 VGPRs)
typedef __attribute__((ext_vector_type(4))) float f32x4;    // MFMA C/D

__device__ __forceinline__ float lo2f(unsigned u) { return __uint_as_float(u << 16); }
__device__ __forceinline__ float hi2f(unsigned u) { return __uint_as_float(u & 0xffff0000u); }
__device__ __forceinline__ unsigned short f2us(float f) {
    __hip_bfloat16 h = __float2bfloat16(f);
    return *(unsigned short*)&h;
}
__device__ __forceinline__ float us2f(unsigned short u) { return __uint_as_float(((unsigned)u) << 16); }
__device__ __forceinline__ unsigned pk2(float a, float b) {
    return ((unsigned)f2us(a)) | (((unsigned)f2us(b)) << 16);
}
__device__ __forceinline__ void up8(uint4 u, float* e) {
    e[0]=lo2f(u.x); e[1]=hi2f(u.x); e[2]=lo2f(u.y); e[3]=hi2f(u.y);
    e[4]=lo2f(u.z); e[5]=hi2f(u.z); e[6]=lo2f(u.w); e[7]=hi2f(u.w);
}
__device__ __forceinline__ uint4 pk8(const float* e) {
    uint4 r; r.x = pk2(e[0],e[1]); r.y = pk2(e[2],e[3]);
    r.z = pk2(e[4],e[5]); r.w = pk2(e[6],e[7]); return r;
}

// async 16B/lane global->LDS
__device__ __forceinline__ void gload_lds16(const void* g, void* l) {
    __builtin_amdgcn_global_load_lds((__attribute__((address_space(1))) void*)g,
                                     (__attribute__((address_space(3))) void*)l, 16, 0, 0);
}

// ---- prep: convert+transpose weights to bf16 [kk][o][f]; zero GN partial buffers ----
__global__ __launch_bounds__(256) void prep_k(
    const float* __restrict__ W1, const float* __restrict__ Wr, const float* __restrict__ W2,
    unsigned short* __restrict__ Wt1, unsigned short* __restrict__ Wtr, unsigned short* __restrict__ Wt2,
    float* __restrict__ part)
{
    int i = blockIdx.x * 256 + threadIdx.x;
    if (i < 32768) {                 // Wt2[kk][o][f] = W2[kk][f][o], F=64
        int kk = i >> 12, rem = i & 4095, o = rem >> 6, f = rem & 63;
        Wt2[i] = f2us(W2[kk * 4096 + f * 64 + o]);
    } else if (i < 49152) {          // Wt1, F=32
        int j = i - 32768;
        int kk = j >> 11, rem = j & 2047, o = rem >> 5, f = rem & 31;
        Wt1[j] = f2us(W1[kk * 2048 + f * 64 + o]);
    } else if (i < 65536) {          // Wtr, F=32
        int j = i - 49152;
        int kk = j >> 11, rem = j & 2047, o = rem >> 5, f = rem & 31;
        Wtr[j] = f2us(Wr[kk * 2048 + f * 64 + o]);
    } else if (i < 66560) {
        part[i - 65536] = 0.f;
    }
}

// ---- reorder x [B,V,32] f32 -> T0 conv1 layout [V][b*32+f] bf16 (packed dwords) ----
__global__ __launch_bounds__(256) void reorder_k(const float* __restrict__ x, unsigned* __restrict__ t0) {
    int idx = blockIdx.x * 256 + threadIdx.x;   // < V*32 dwords
    int v = idx >> 5, j2 = idx & 31;
    int b = j2 >> 4, f0 = (j2 & 15) * 2;
    const float* p = x + ((size_t)b * V + v) * 32 + f0;
    t0[idx] = pk2(p[0], p[1]);
}

// ---- SpMM Chebyshev step: zn = 2*(L@zc) - zp (bf16 rows). 32B (2 uint4) per thread. ----
template<int THR, bool FIRST>
__global__ __launch_bounds__(256) void spmm_step(
    const uint4* __restrict__ zc, const uint4* __restrict__ zp, uint4* __restrict__ zn,
    const float* __restrict__ vals, const int* __restrict__ col)
{
    constexpr int L4 = THR * 2;                   // uint4 per row
    int tid = blockIdx.x * 256 + threadIdx.x;     // over V*THR
    int v = tid / THR;
    int c = (tid - v * THR) * 2;
    int base = v * NNZ;
    float t[16];
    #pragma unroll
    for (int i = 0; i < 16; ++i) t[i] = 0.f;
    #pragma unroll
    for (int n = 0; n < NNZ; ++n) {
        float a = vals[base + n];
        int cc = col[base + n];
        const uint4* p = zc + (size_t)cc * L4 + c;
        uint4 u0 = p[0];
        uint4 u1 = p[1];
        t[0] += a * lo2f(u0.x); t[1] += a * hi2f(u0.x);
        t[2] += a * lo2f(u0.y); t[3] += a * hi2f(u0.y);
        t[4] += a * lo2f(u0.z); t[5] += a * hi2f(u0.z);
        t[6] += a * lo2f(u0.w); t[7] += a * hi2f(u0.w);
        t[8]  += a * lo2f(u1.x); t[9]  += a * hi2f(u1.x);
        t[10] += a * lo2f(u1.y); t[11] += a * hi2f(u1.y);
        t[12] += a * lo2f(u1.z); t[13] += a * hi2f(u1.z);
        t[14] += a * lo2f(u1.w); t[15] += a * hi2f(u1.w);
    }
    if (!FIRST) {
        const uint4* pp = zp + (size_t)v * L4 + c;
        uint4 p0 = pp[0];
        uint4 p1 = pp[1];
        t[0] = 2.f*t[0] - lo2f(p0.x); t[1] = 2.f*t[1] - hi2f(p0.x);
        t[2] = 2.f*t[2] - lo2f(p0.y); t[3] = 2.f*t[3] - hi2f(p0.y);
        t[4] = 2.f*t[4] - lo2f(p0.z); t[5] = 2.f*t[5] - hi2f(p0.z);
        t[6] = 2.f*t[6] - lo2f(p0.w); t[7] = 2.f*t[7] - hi2f(p0.w);
        t[8]  = 2.f*t[8]  - lo2f(p1.x); t[9]  = 2.f*t[9]  - hi2f(p1.x);
        t[10] = 2.f*t[10] - lo2f(p1.y); t[11] = 2.f*t[11] - hi2f(p1.y);
        t[12] = 2.f*t[12] - lo2f(p1.z); t[13] = 2.f*t[13] - hi2f(p1.z);
        t[14] = 2.f*t[14] - lo2f(p1.w); t[15] = 2.f*t[15] - hi2f(p1.w);
    }
    uint4 r0, r1;
    r0.x = pk2(t[0], t[1]);  r0.y = pk2(t[2], t[3]);
    r0.z = pk2(t[4], t[5]);  r0.w = pk2(t[6], t[7]);
    r1.x = pk2(t[8], t[9]);  r1.y = pk2(t[10], t[11]);
    r1.z = pk2(t[12], t[13]); r1.w = pk2(t[14], t[15]);
    uint4* q = zn + (size_t)v * L4 + c;
    q[0] = r0;
    q[1] = r1;
}

// ---- MFMA GEMM (R11-proven): 64-row tile, NPH staging phases, B in VGPRs,
// ds_read_b128+MFMA inner loop, LDS-transposed coalesced epilogue + GN partials.
// DUAL res output now bf16 (RES buffer) for halved write traffic. ----
template<int F, int NKK, int NPH, bool DUAL, bool INIT, bool FINAL>
__global__ __launch_bounds__(256) void mfma_gemm(
    const unsigned short* __restrict__ T,
    const unsigned short* __restrict__ WtA, const unsigned short* __restrict__ WtB,
    const float* __restrict__ biasA, const float* __restrict__ biasB,
    unsigned short* __restrict__ ACC, unsigned short* __restrict__ resOut,
    float* __restrict__ part)
{
    constexpr int KPP = NKK / NPH;
    constexpr int CPR = F / 4;
    constexpr int FH = F / 32;
    constexpr int RST = 68;
    constexpr int STAGE_SH = KPP * 64 * 2 * F;
    constexpr int TRANS_SH = (DUAL ? 2 : 1) * 2 * 64 * RST * 2;
    constexpr int SH = STAGE_SH > TRANS_SH ? STAGE_SH : TRANS_SH;
    __shared__ unsigned short shraw[SH];
    __shared__ float sGrp[32];

    unsigned short* tile = shraw;
    float* accbuf  = (float*)shraw;
    float* dualbuf = accbuf + 2 * 64 * RST;

    int wv = threadIdx.x >> 6, lane = threadIdx.x & 63;
    int quad = lane >> 4, l15 = lane & 15;
    int v0 = blockIdx.x * 64;
    int ot = wv;

    bf16x8 bw[NKK][FH];
    bf16x8 bd[NKK][FH];
    f32x4 acc[4][2];
    f32x4 accd[4][2];

    #pragma unroll
    for (int ph = 0; ph < NPH; ++ph) {
        if (ph > 0) __syncthreads();
        #pragma unroll
        for (int i = 0; i < (KPP * 64 * CPR) / 256; ++i) {
            int s = (i * 4 + wv) * 64 + lane;
            int kkl = s / (64 * CPR);
            int ws = s - kkl * 64 * CPR;
            int row = ws / CPR;
            int cl = ws - row * CPR;
            int cg2 = (cl & ~7) | ((cl & 7) ^ (row & 7));
            const unsigned short* gp =
                T + ((size_t)(ph * KPP + kkl) * V + v0 + row) * (2 * F) + cg2 * 8;
            gload_lds16(gp, tile + (size_t)(i * 4 + wv) * 64 * 8);
        }
        if (ph == 0) {
            #pragma unroll
            for (int kk = 0; kk < NKK; ++kk)
                #pragma unroll
                for (int fh = 0; fh < FH; ++fh) {
                    size_t brow = ((size_t)kk * 64 + ot * 16 + l15) * F + fh * 32 + quad * 8;
                    bw[kk][fh] = *(const bf16x8*)(const void*)(WtA + brow);
                    if constexpr (DUAL) bd[kk][fh] = *(const bf16x8*)(const void*)(WtB + brow);
                }
            #pragma unroll
            for (int m = 0; m < 4; ++m)
                #pragma unroll
                for (int b = 0; b < 2; ++b) {
                    acc[m][b] = (f32x4){0.f, 0.f, 0.f, 0.f};
                    if constexpr (DUAL) accd[m][b] = (f32x4){0.f, 0.f, 0.f, 0.f};
                }
        }
        __syncthreads();
        #pragma unroll
        for (int kkl = 0; kkl < KPP; ++kkl) {
            int kk = ph * KPP + kkl;
            #pragma unroll
            for (int fh = 0; fh < FH; ++fh) {
                #pragma unroll
                for (int m = 0; m < 4; ++m) {
                    int r = m * 16 + l15;
                    int rx = r & 7;
                    const unsigned short* rbase = tile + ((size_t)kkl * 64 + r) * 2 * F;
                    #pragma unroll
                    for (int b = 0; b < 2; ++b) {
                        int c0 = b * (CPR / 2) + fh * 4 + quad;
                        int s0 = (c0 & ~7) | ((c0 & 7) ^ rx);
                        bf16x8 a = *(const bf16x8*)(const void*)(rbase + s0 * 8);
                        acc[m][b] = __builtin_amdgcn_mfma_f32_16x16x32_bf16(a, bw[kk][fh], acc[m][b], 0, 0, 0);
                        if constexpr (DUAL)
                            accd[m][b] = __builtin_amdgcn_mfma_f32_16x16x32_bf16(a, bd[kk][fh], accd[m][b], 0, 0, 0);
                    }
                }
            }
        }
    }

    __syncthreads();
    int o = ot * 16 + l15;
    float bia = FINAL ? biasA[o] : 0.f;
    float biaB = DUAL ? biasB[o] : 0.f;
    #pragma unroll
    for (int m = 0; m < 4; ++m)
        #pragma unroll
        for (int b = 0; b < 2; ++b)
            #pragma unroll
            for (int rr = 0; rr < 4; ++rr) {
                int r = m * 16 + quad * 4 + rr;
                accbuf[(b * 64 + r) * RST + o] = acc[m][b][rr] + bia;
                if constexpr (DUAL) dualbuf[(b * 64 + r) * RST + o] = accd[m][b][rr] + biaB;
            }
    if constexpr (FINAL) {
        if (threadIdx.x < 32) sGrp[threadIdx.x] = 0.f;
    }
    __syncthreads();

    // ACC: 1024 uint4 chunks (8 bf16 each), coalesced
    #pragma unroll
    for (int j = 0; j < 4; ++j) {
        int cid = threadIdx.x + 256 * j;
        int g = cid & 7, r = (cid >> 3) & 63, b = cid >> 9;
        int o0 = g * 8;
        const float* src = accbuf + (b * 64 + r) * RST + o0;
        float e[8];
        #pragma unroll
        for (int i = 0; i < 8; ++i) e[i] = src[i];
        size_t gidx = ((size_t)b * V + v0 + r) * 64 + o0;
        if constexpr (!INIT) {
            uint4 old = *(const uint4*)(const void*)(ACC + gidx);
            e[0] += lo2f(old.x); e[1] += hi2f(old.x);
            e[2] += lo2f(old.y); e[3] += hi2f(old.y);
            e[4] += lo2f(old.z); e[5] += hi2f(old.z);
            e[6] += lo2f(old.w); e[7] += hi2f(old.w);
        }
        uint4 pk;
        pk.x = pk2(e[0], e[1]); pk.y = pk2(e[2], e[3]);
        pk.z = pk2(e[4], e[5]); pk.w = pk2(e[6], e[7]);
        *(uint4*)(void*)(ACC + gidx) = pk;
        if constexpr (FINAL) {
            float s = 0.f, q = 0.f;
            #pragma unroll
            for (int i = 0; i < 8; ++i) { s += e[i]; q += e[i] * e[i]; }
            atomicAdd(&sGrp[b * 8 + g], s);
            atomicAdd(&sGrp[16 + b * 8 + g], q);
        }
    }
    if constexpr (DUAL) {
        // res: 1024 uint4 chunks bf16, coalesced
        #pragma unroll
        for (int j = 0; j < 4; ++j) {
            int cid = threadIdx.x + 256 * j;
            int g = cid & 7, r = (cid >> 3) & 63, b = cid >> 9;
            int o0 = g * 8;
            const float* src = dualbuf + (b * 64 + r) * RST + o0;
            float e[8];
            #pragma unroll
            for (int i = 0; i < 8; ++i) e[i] = src[i];
            uint4 pk;
            pk.x = pk2(e[0], e[1]); pk.y = pk2(e[2], e[3]);
            pk.z = pk2(e[4], e[5]); pk.w = pk2(e[6], e[7]);
            *(uint4*)(void*)(resOut + ((size_t)b * V + v0 + r) * 64 + o0) = pk;
        }
    }
    if constexpr (FINAL) {
        __syncthreads();
        if (threadIdx.x < 16) {
            atomicAdd(&part[threadIdx.x * 2],     sGrp[threadIdx.x]);
            atomicAdd(&part[threadIdx.x * 2 + 1], sGrp[16 + threadIdx.x]);
        }
    }
}

// ---- GN1 + LeakyReLU (stats inline from PART): ACC bf16 -> conv2 T0 [V][b*64+o] ----
__global__ __launch_bounds__(256) void gn_apply(const unsigned short* __restrict__ ACC,
                                                const float* __restrict__ part,
                                                const float* __restrict__ gamma, const float* __restrict__ beta,
                                                unsigned* __restrict__ zout) {
    int idx = blockIdx.x * 256 + threadIdx.x;   // < V*16 (8-channel chunks)
    int v = idx >> 4, j = idx & 15;             // j = b*8+g
    int b = j >> 3, g = j & 7;
    const float N = (float)V * 8.f;
    float mean = part[j * 2] / N;
    float rstd = rsqrtf(part[j * 2 + 1] / N - mean * mean + EPSV);
    int o0 = g * 8;
    uint4 aa = *(const uint4*)(const void*)(ACC + ((size_t)b * V + v) * 64 + o0);
    float e[8];
    up8(aa, e);
    float y[8];
    #pragma unroll
    for (int i = 0; i < 8; ++i) {
        float t = (e[i] - mean) * rstd * gamma[o0 + i] + beta[o0 + i];
        y[i] = t > 0.f ? t : SLOPE * t;
    }
    uint4 pk;
    pk.x = pk2(y[0], y[1]); pk.y = pk2(y[2], y[3]);
    pk.z = pk2(y[4], y[5]); pk.w = pk2(y[6], y[7]);
    *(uint4*)(void*)(zout + (size_t)v * 64 + b * 32 + g * 4) = pk;
}

// ---- final (stats inline): out = LeakyReLU(GN2(ACC)) + RES (bf16) ----
__global__ __launch_bounds__(256) void final_out(const unsigned short* __restrict__ ACC,
                                                 const unsigned short* __restrict__ RES,
                                                 float* __restrict__ out,
                                                 const float* __restrict__ part,
                                                 const float* __restrict__ gamma, const float* __restrict__ beta) {
    int idx = blockIdx.x * 256 + threadIdx.x;   // < 2*V*8 (8-channel chunks)
    int b = idx >= V * 8 ? 1 : 0;
    int r = idx - b * V * 8;
    int v = r >> 3, g = r & 7;
    int j = b * 8 + g;
    const float N = (float)V * 8.f;
    float mean = part[j * 2] / N;
    float rstd = rsqrtf(part[j * 2 + 1] / N - mean * mean + EPSV);
    int o0 = g * 8;
    size_t base = ((size_t)b * V + v) * 64 + o0;
    uint4 aa = *(const uint4*)(const void*)(ACC + base);
    uint4 rr = *(const uint4*)(const void*)(RES + base);
    float e[8], rs[8];
    up8(aa, e); up8(rr, rs);
    float y[8];
    #pragma unroll
    for (int i = 0; i < 8; ++i) {
        float t = (e[i] - mean) * rstd * gamma[o0 + i] + beta[o0 + i];
        t = t > 0.f ? t : SLOPE * t;
        y[i] = t + rs[i];
    }
    float4 w0 = { y[0], y[1], y[2], y[3] };
    float4 w1 = { y[4], y[5], y[6], y[7] };
    *(float4*)(void*)(out + base) = w0;
    *(float4*)(void*)(out + base + 4) = w1;
}

extern "C" void kernel_launch(void* const* d_in, const int* in_sizes, int n_in,
                              void* d_out, int out_size, void* d_ws, size_t ws_size,
                              hipStream_t stream) {
    const float* x    = (const float*)d_in[0];
    const float* vals = (const float*)d_in[1];
    const int*   col  = (const int*)d_in[3];
    const float* W1   = (const float*)d_in[4];
    const float* b1   = (const float*)d_in[5];
    const float* g1   = (const float*)d_in[6];
    const float* be1  = (const float*)d_in[7];
    const float* W2   = (const float*)d_in[8];
    const float* b2   = (const float*)d_in[9];
    const float* g2   = (const float*)d_in[10];
    const float* be2  = (const float*)d_in[11];
    const float* Wr   = (const float*)d_in[12];
    const float* br   = (const float*)d_in[13];
    float* out = (float*)d_out;

    // workspace: TS bf16 8*[V][128] 100.7MB | ACC bf16 [2][V][64] | RES bf16 [2][V][64]
    //            | Wt1/Wtr/Wt2 bf16 128KB | PART1/PART2 f32
    unsigned short* TS  = (unsigned short*)d_ws;
    unsigned short* ACC = TS + (size_t)8 * V * 128;
    unsigned short* RES = ACC + (size_t)2 * V * 64;
    unsigned short* Wt1 = RES + (size_t)2 * V * 64;
    unsigned short* Wtr = Wt1 + 8 * 64 * 32;
    unsigned short* Wt2 = Wtr + 8 * 64 * 32;
    float* PART1 = (float*)(Wt2 + 8 * 64 * 64);
    float* PART2 = PART1 + 32;

    prep_k<<<260, 256, 0, stream>>>(W1, Wr, W2, Wt1, Wtr, Wt2, PART1);

    // ---- conv1 basis: T0..T7 in 8 slots of [V][64] bf16 ----
    uint4* T1s[8];
    for (int k = 0; k < 8; ++k) T1s[k] = (uint4*)(TS + (size_t)k * V * 64);

    reorder_k<<<V * 32 / 256, 256, 0, stream>>>(x, (unsigned*)T1s[0]);
    spmm_step<4, true><<<V * 4 / 256, 256, 0, stream>>>(T1s[0], nullptr, T1s[1], vals, col);
    for (int k = 2; k < 8; ++k)
        spmm_step<4, false><<<V * 4 / 256, 256, 0, stream>>>(T1s[k-1], T1s[k-2], T1s[k], vals, col);

    // conv1 + res GEMM over all 8 T_k
    mfma_gemm<32, 8, 1, true, true, true><<<V / 64, 256, 0, stream>>>(
        TS, Wt1, Wtr, b1, br, ACC, RES, PART1);

    // ---- conv2: GN1(h1) as T0; all 8 T_k in distinct slots ----
    uint4* T2s[8];
    for (int k = 0; k < 8; ++k) T2s[k] = (uint4*)(TS + (size_t)k * V * 128);

    gn_apply<<<V * 16 / 256, 256, 0, stream>>>(ACC, PART1, g1, be1, (unsigned*)T2s[0]);
    spmm_step<8, true><<<V * 8 / 256, 256, 0, stream>>>(T2s[0], nullptr, T2s[1], vals, col);
    for (int k = 2; k < 8; ++k)
        spmm_step<8, false><<<V * 8 / 256, 256, 0, stream>>>(T2s[k-1], T2s[k-2], T2s[k], vals, col);

    // conv2: single GEMM, two staging phases
    mfma_gemm<64, 8, 2, false, true, true><<<V / 64, 256, 0, stream>>>(
        TS, Wt2, nullptr, b2, nullptr, ACC, nullptr, PART2);

    final_out<<<2 * V * 8 / 256, 256, 0, stream>>>(ACC, RES, out, PART2, g2, be2);
}